// Round 17
// baseline (96.366 us; speedup 1.0000x reference)
//
#include <hip/hip_runtime.h>
#include <hip/hip_bf16.h>

#define T_SEQ 2048
#define H_CNT 16
#define B_SZ  2
#define QKV_LD 896
#define KOFF   512
#define VOFF   640

typedef float  f32x4   __attribute__((ext_vector_type(4)));
typedef float  f32x16  __attribute__((ext_vector_type(16)));
typedef __bf16 bf16x8  __attribute__((ext_vector_type(8)));

static __device__ __forceinline__ ushort f2bf(float f) {
    union { float f; unsigned u; } v; v.f = f;
    unsigned u = v.u;
    unsigned r = (u + 0x7fffu + ((u >> 16) & 1u)) >> 16;
    return (ushort)r;
}
static __device__ __forceinline__ float bf2f(unsigned x) {
    union { unsigned u; float f; } v; v.u = x << 16; return v.f;
}
static __device__ __forceinline__ unsigned pack2bf(float a, float b) {
    union { __bf16 h[2]; unsigned u; } pk;
    pk.h[0] = (__bf16)a; pk.h[1] = (__bf16)b;
    return pk.u;
}

static __device__ __forceinline__ f32x4 mfma16(bf16x8 a, bf16x8 b, f32x4 c) {
    return __builtin_amdgcn_mfma_f32_16x16x32_bf16(a, b, c, 0, 0, 0);
}
static __device__ __forceinline__ f32x16 mfma32(bf16x8 a, bf16x8 b, f32x16 c) {
    return __builtin_amdgcn_mfma_f32_32x32x16_bf16(a, b, c, 0, 0, 0);
}

// async global->LDS, 16B per lane; LDS dest is wave-uniform base + lane*16
static __device__ __forceinline__ void gl_lds16(const void* g, void* l) {
    __builtin_amdgcn_global_load_lds((const __attribute__((address_space(1))) void*)g,
                                     (__attribute__((address_space(3))) void*)l, 16, 0, 0);
}

// ---------------------------------------------------------------------------
// Fused input prep (one launch): flat grid 3968.
//   n < 2048 : fp32 -> bf16 convert of x (8 elems/thread), block n.
//   n >= 2048: weight transpose fp32 [1024][C] -> bf16 [C][1024].
// ---------------------------------------------------------------------------
__global__ __launch_bounds__(256) void prep_inputs(const float* __restrict__ xin,
                                                   ushort* __restrict__ xb,
                                                   const float* __restrict__ Wq,
                                                   const float* __restrict__ Wk,
                                                   const float* __restrict__ Wv,
                                                   const float* __restrict__ Wp,
                                                   ushort* __restrict__ Wqkvt,
                                                   ushort* __restrict__ Wpt) {
    __shared__ float tile[32][33];
    const int n = blockIdx.x;
    if (n < 2048) {
        const int i = n * 256 + threadIdx.x;
        const float4 v0 = reinterpret_cast<const float4*>(xin)[i * 2];
        const float4 v1 = reinterpret_cast<const float4*>(xin)[i * 2 + 1];
        uint4 o;
        o.x = (unsigned)f2bf(v0.x) | ((unsigned)f2bf(v0.y) << 16);
        o.y = (unsigned)f2bf(v0.z) | ((unsigned)f2bf(v0.w) << 16);
        o.z = (unsigned)f2bf(v1.x) | ((unsigned)f2bf(v1.y) << 16);
        o.w = (unsigned)f2bf(v1.z) | ((unsigned)f2bf(v1.w) << 16);
        reinterpret_cast<uint4*>(xb)[i] = o;
        return;
    }
    const int m = n - 2048;
    const int x = m % 60;
    const int y = m / 60;
    const float* src; ushort* dst; int C, cx;
    if (x < 16)      { src = Wq; dst = Wqkvt;              C = 512;  cx = x; }
    else if (x < 20) { src = Wk; dst = Wqkvt + 512 * 1024; C = 128;  cx = x - 16; }
    else if (x < 28) { src = Wv; dst = Wqkvt + 640 * 1024; C = 256;  cx = x - 20; }
    else             { src = Wp; dst = Wpt;                C = 1024; cx = x - 28; }
    const int tx = threadIdx.x & 31, ty = threadIdx.x >> 5;
    const int r0 = y * 32, c0 = cx * 32;
#pragma unroll
    for (int i = 0; i < 32; i += 8)
        tile[ty + i][tx] = src[(size_t)(r0 + ty + i) * C + c0 + tx];
    __syncthreads();
#pragma unroll
    for (int i = 0; i < 32; i += 8)
        dst[(size_t)(c0 + ty + i) * 1024 + r0 + tx] = f2bf(tile[tx][ty + i]);
}

// ---------------------------------------------------------------------------
// bf16 MFMA GEMM (R13/R16-proven): global_load_lds staging, BK=128.
// Tile 64x128, 4 waves (2x2), wave tile 32x64. V_SPLIT fuses V transpose.
// ---------------------------------------------------------------------------
template <bool OUT_BF16, bool V_SPLIT>
__global__ __launch_bounds__(256) void gemm_bf16(const ushort* __restrict__ A,
                                                 const ushort* __restrict__ Bt,
                                                 const float* __restrict__ bias,
                                                 void* __restrict__ Cout,
                                                 ushort* __restrict__ vTb,
                                                 int M, int N, int K) {
    __shared__ __align__(16) ushort As[4][64 * 32];
    __shared__ __align__(16) ushort Bs[4][128 * 32];

    const int tid = threadIdx.x;
    const int w = tid >> 6, l = tid & 63;
    const int bm = blockIdx.y * 64, bn = blockIdx.x * 128;
    const int wr = (w >> 1) * 32, wc = (w & 1) * 64;
    const int lr = l & 15, lk = (l >> 4) * 8;
    const int crow = l >> 2, ck8 = (l & 3) * 8;

    const ushort* Ag  = A + (size_t)(bm + w * 16 + crow) * K + ck8;
    const ushort* Bg0 = Bt + (size_t)(bn + w * 16 + crow) * K + ck8;
    const ushort* Bg1 = Bt + (size_t)(bn + (w + 4) * 16 + crow) * K + ck8;

    f32x4 acc[2][4];
#pragma unroll
    for (int m = 0; m < 2; ++m)
#pragma unroll
        for (int n = 0; n < 4; ++n) acc[m][n] = (f32x4){0.f, 0.f, 0.f, 0.f};

    for (int k0 = 0; k0 < K; k0 += 128) {
        __syncthreads();
#pragma unroll
        for (int kk = 0; kk < 4; ++kk) {
            gl_lds16(Ag + k0 + kk * 32, &As[kk][w * 16 * 32]);
            gl_lds16(Bg0 + k0 + kk * 32, &Bs[kk][w * 16 * 32]);
            gl_lds16(Bg1 + k0 + kk * 32, &Bs[kk][(w + 4) * 16 * 32]);
        }
        __syncthreads();

#pragma unroll
        for (int kk = 0; kk < 4; ++kk) {
            bf16x8 af[2], bfr[4];
#pragma unroll
            for (int m = 0; m < 2; ++m)
                af[m] = *reinterpret_cast<const bf16x8*>(&As[kk][(wr + m * 16 + lr) * 32 + lk]);
#pragma unroll
            for (int n = 0; n < 4; ++n)
                bfr[n] = *reinterpret_cast<const bf16x8*>(&Bs[kk][(wc + n * 16 + lr) * 32 + lk]);
#pragma unroll
            for (int m = 0; m < 2; ++m)
#pragma unroll
                for (int n = 0; n < 4; ++n)
                    acc[m][n] = mfma16(af[m], bfr[n], acc[m][n]);
        }
    }

    const int orow = bm + wr + (l >> 4) * 4;
    const int ocol0 = bn + wc + lr;
#pragma unroll
    for (int m = 0; m < 2; ++m)
#pragma unroll
        for (int n = 0; n < 4; ++n) {
            const int col = ocol0 + n * 16;
            if (V_SPLIT && col >= VOFF) {
                uint2 pk;
                pk.x = (unsigned)f2bf(acc[m][n][0]) | ((unsigned)f2bf(acc[m][n][1]) << 16);
                pk.y = (unsigned)f2bf(acc[m][n][2]) | ((unsigned)f2bf(acc[m][n][3]) << 16);
                const int row0 = orow + m * 16;
                const size_t vidx = (size_t)(row0 >> 11) * 524288 +
                                    (size_t)(col - VOFF) * 2048 + (row0 & 2047);
                *reinterpret_cast<uint2*>(&vTb[vidx]) = pk;
                continue;
            }
            const float bv = OUT_BF16 ? 0.0f : bias[col];
#pragma unroll
            for (int r = 0; r < 4; ++r) {
                const size_t idx = (size_t)(orow + m * 16 + r) * N + col;
                if constexpr (OUT_BF16)
                    reinterpret_cast<ushort*>(Cout)[idx] = f2bf(acc[m][n][r]);
                else
                    reinterpret_cast<float*>(Cout)[idx] = acc[m][n][r] + bv;
            }
        }
}

// ---------------------------------------------------------------------------
// Flash attention, split-KV partial kernel. Grid = 1024 linear, 512 thr.
// Decode (dispatch-balanced): c=m&255, rho=m>>8; g=c&3, b=(c>>2)&1, j=c>>3;
// t = (rho&1) ? 63-j : j; half = rho>>1.  Column c hosts both halves of
// t=j AND t=63-j -> every presumed-CU column sums to exactly 17 tile-iters;
// 1024 blocks > 512 resident slots -> dynamic backfill balances the rest.
// Each block computes keys [itbeg*128, min(itend*128,nkeys)) of q-tile t for
// 4 heads (hd=w&3) x 2 key-subgroups (grp=w>>2) -- inner body byte-identical
// to R13-proven attn_mfma9. Epilogue writes UNNORMALIZED partials:
// part_o[area][hd][q][d] bf16 (area = slot*2+half, slot = t*8+g*2+b) and
// part_l[area][hd][q] f32. Empty halves write zero partials via the same
// uniform epilogue (o,ls start at zero). Deterministic: no atomics.
// ---------------------------------------------------------------------------
#define LDK 40
#define LDV 136

__global__ __launch_bounds__(512) void attn_part(const ushort* __restrict__ qkv,
                                                 const ushort* __restrict__ vT,
                                                 ushort* __restrict__ part_o,
                                                 float* __restrict__ part_l) {
    __shared__ __align__(16) ushort Ks[2][128 * LDK];   // 20.5 KB
    __shared__ __align__(16) ushort Vs[2][64 * LDV];    // 34.8 KB
    __shared__ float lsred[4][32];

    const int tid = threadIdx.x;
    const int w = tid >> 6, l = tid & 63;
    const int lq = l & 31;
    const int hi = l >> 5;
    const int m = blockIdx.x;
    const int c = m & 255, rho = m >> 8;
    const int g = c & 3, b = (c >> 2) & 1, j = c >> 3;
    const int t = (rho & 1) ? (63 - j) : j;
    const int half = rho >> 1;
    const int i0 = t * 32;
    const int hd = w & 3, grp = w >> 2;
    const int h = g + 4 * hd;

    const int nkeys = i0 + 32;
    const int ntiles = (nkeys + 127) >> 7;
    const int tiles0 = (ntiles + 1) >> 1;
    const int itbeg = half ? tiles0 : 0;
    const int itend = half ? ntiles : tiles0;
    const int jt0 = itbeg * 128, jtend = itend * 128;

    const float slope = exp2f(-0.5f * (float)(h + 1));
    const float k1 = 0.17677669529663687f * 1.4426950408889634f;  // scale*log2e
    const float k2 = slope * k1;
    const int Wint = (int)(275.0f / slope);

    // K staging: row ksd of 128, chunk kc4 of 4
    const int ksd = tid >> 2, kc4 = tid & 3;
    const ushort* kgp = qkv + (size_t)b * T_SEQ * QKV_LD + KOFF + g * 32 +
                        (size_t)ksd * QKV_LD + kc4 * 8;
    // V staging: d-row vsd of 64, vj of 8 -> spans {vs0, vs0+1}, chunk vc4
    const int vsd = tid >> 3, vj = tid & 7;
    const int vs0 = (vj >> 2) << 1, vc4 = vj & 3;
    const int voff = (vc4 & 1) * 4 + (vc4 >> 1) * 16;  // permuted slot (ushorts)
    const ushort* vgp = vT + ((size_t)b * 256 + g * 64 + vsd) * T_SEQ + vs0 * 32 + vc4 * 8;
    const int vl0 = vsd * LDV + vs0 * 32 + voff;
    const int vl1 = vsd * LDV + (vs0 + 1) * 32 + voff;

    // combine scratch (16 KB), aliased onto Vs after loop reads complete
    float* red = reinterpret_cast<float*>(&Vs[0][0]);
    const int sidx = (hd * 64 + l) * 16;

    const ushort* qrow = qkv + ((size_t)(b * T_SEQ + i0 + lq)) * QKV_LD + h * 32 + hi * 8;
    const bf16x8 qa = *reinterpret_cast<const bf16x8*>(qrow);
    const bf16x8 qb = *reinterpret_cast<const bf16x8*>(qrow + 16);

    f32x16 o0, o1;
#pragma unroll
    for (int r = 0; r < 16; ++r) { o0[r] = 0.0f; o1[r] = 0.0f; }
    float ls = 0.0f;

    // prologue loads at jt0 (guarded at 32-key granularity)
    uint4 kreg, vr0, vr1;
    if (jt0 < jtend) {
        if (jt0 + ksd < nkeys) kreg = *reinterpret_cast<const uint4*>(kgp + (size_t)jt0 * QKV_LD);
        if (jt0 + vs0 * 32 < nkeys) vr0 = *reinterpret_cast<const uint4*>(vgp + jt0);
        if (jt0 + vs0 * 32 + 32 < nkeys) vr1 = *reinterpret_cast<const uint4*>(vgp + jt0 + 32);
    }

    int cur = 0;
    for (int jt = jt0; jt < jtend; jt += 128) {
        // ---- stage buf[cur] ----
        *reinterpret_cast<uint4*>(&Ks[cur][ksd * LDK + kc4 * 8]) = kreg;
        *reinterpret_cast<uint2*>(&Vs[cur][vl0]) = make_uint2(vr0.x, vr0.y);
        *reinterpret_cast<uint2*>(&Vs[cur][vl0 + 8]) = make_uint2(vr0.z, vr0.w);
        *reinterpret_cast<uint2*>(&Vs[cur][vl1]) = make_uint2(vr1.x, vr1.y);
        *reinterpret_cast<uint2*>(&Vs[cur][vl1 + 8]) = make_uint2(vr1.z, vr1.w);
        // ---- issue next-tile loads (guarded) ----
        const int jn = jt + 128;
        if (jn < jtend) {
            if (jn + ksd < nkeys)
                kreg = *reinterpret_cast<const uint4*>(kgp + (size_t)jn * QKV_LD);
            if (jn + vs0 * 32 < nkeys)
                vr0 = *reinterpret_cast<const uint4*>(vgp + jn);
            if (jn + vs0 * 32 + 32 < nkeys)
                vr1 = *reinterpret_cast<const uint4*>(vgp + jn + 32);
        }
        __syncthreads();   // buf[cur] ready

#pragma unroll
        for (int s = 0; s < 2; ++s) {
            const int si = s * 2 + grp;
            const int jts = jt + si * 32;
            if (jts < nkeys && jts + 31 >= i0 - Wint) {
                const bf16x8 ka = *reinterpret_cast<const bf16x8*>(&Ks[cur][(si * 32 + lq) * LDK + hi * 8]);
                const bf16x8 kb2 = *reinterpret_cast<const bf16x8*>(&Ks[cur][(si * 32 + lq) * LDK + 16 + hi * 8]);
                f32x16 p;
#pragma unroll
                for (int r = 0; r < 16; ++r) p[r] = 0.0f;
                __builtin_amdgcn_s_setprio(1);
                p = mfma32(ka, qa, p);
                p = mfma32(kb2, qb, p);
                __builtin_amdgcn_s_setprio(0);

                const int dlt = jts + 4 * hi - i0 - lq;
                const float base2 = k2 * (float)dlt;
                float pe[16];
                if (jts + 31 > i0) {   // diag subtile (uniform branch)
#pragma unroll
                    for (int r = 0; r < 16; ++r) {
                        const int off = (r & 3) + 8 * (r >> 2);
                        const float arg = fmaf(p[r], k1, fmaf((float)off, k2, base2));
                        float e = exp2f(arg);
                        if (dlt + off > 0) e = 0.0f;
                        ls += e;
                        pe[r] = e;
                    }
                } else {
#pragma unroll
                    for (int r = 0; r < 16; ++r) {
                        const int off = (r & 3) + 8 * (r >> 2);
                        const float arg = fmaf(p[r], k1, fmaf((float)off, k2, base2));
                        const float e = exp2f(arg);
                        ls += e;
                        pe[r] = e;
                    }
                }
                union { unsigned u[4]; bf16x8 v; } A1, A2;
#pragma unroll
                for (int j2 = 0; j2 < 4; ++j2) A1.u[j2] = pack2bf(pe[2 * j2], pe[2 * j2 + 1]);
#pragma unroll
                for (int j2 = 0; j2 < 4; ++j2) A2.u[j2] = pack2bf(pe[8 + 2 * j2], pe[9 + 2 * j2]);

                const int vr0i = lq * LDV + si * 32;
                const int vr1i = (32 + lq) * LDV + si * 32;
                const bf16x8 v00 = *reinterpret_cast<const bf16x8*>(&Vs[cur][vr0i + hi * 8]);
                const bf16x8 v01 = *reinterpret_cast<const bf16x8*>(&Vs[cur][vr0i + 16 + hi * 8]);
                const bf16x8 v10 = *reinterpret_cast<const bf16x8*>(&Vs[cur][vr1i + hi * 8]);
                const bf16x8 v11 = *reinterpret_cast<const bf16x8*>(&Vs[cur][vr1i + 16 + hi * 8]);
                __builtin_amdgcn_s_setprio(1);
                o0 = mfma32(A1.v, v00, o0);
                o0 = mfma32(A2.v, v01, o0);
                o1 = mfma32(A1.v, v10, o1);
                o1 = mfma32(A2.v, v11, o1);
                __builtin_amdgcn_s_setprio(0);
            }
        }
        cur ^= 1;
    }

    // ---- 2-way cross-grp combine (proven tree), then write PARTIALS ----
    const float ls2 = ls + __shfl_xor(ls, 32);
    __syncthreads();   // all loop reads of Vs done -> safe to reuse as scratch
    if (grp == 0) {
#pragma unroll
        for (int r = 0; r < 16; ++r) red[sidx + r] = o0[r];
        if (hi == 0) lsred[hd][lq] = ls2;
    }
    __syncthreads();
    float lst = 0.0f;
    if (grp == 1) {
#pragma unroll
        for (int r = 0; r < 16; ++r) o0[r] += red[sidx + r];
        lst = ls2 + lsred[hd][lq];
    }
    __syncthreads();
    if (grp == 0) {
#pragma unroll
        for (int r = 0; r < 16; ++r) red[sidx + r] = o1[r];
    }
    __syncthreads();
    if (grp == 1) {
#pragma unroll
        for (int r = 0; r < 16; ++r) o1[r] += red[sidx + r];
        const int slot = t * 8 + g * 2 + b;
        const int area = slot * 2 + half;
        if (hi == 0) part_l[area * 128 + hd * 32 + lq] = lst;
#pragma unroll
        for (int r = 0; r < 16; ++r) {
            const int qr = (r & 3) + 8 * (r >> 2) + 4 * hi;
            const size_t base = ((size_t)(area * 4 + hd) * 32 + qr) * 64;
            part_o[base + lq] = f2bf(o0[r]);
            part_o[base + 32 + lq] = f2bf(o1[r]);
        }
    }
}

// ---------------------------------------------------------------------------
// Combine kernel: ctx = (o_half0 + o_half1) / (l_half0 + l_half1).
// Grid 512 (one slot per block), 256 threads. Deterministic, no atomics.
// ---------------------------------------------------------------------------
__global__ __launch_bounds__(256) void attn_combine(const ushort* __restrict__ part_o,
                                                    const float* __restrict__ part_l,
                                                    ushort* __restrict__ ctx) {
    const int s = blockIdx.x;                 // slot = t*8 + g*2 + b
    const int t = s >> 3, g = (s >> 1) & 3, b = s & 1;
    const int tid = threadIdx.x;
    const int row = tid >> 1;                 // 0..127
    const int hd = row >> 5, q = row & 31;
    const int dh = (tid & 1) * 32;
    const int aA = s * 2, aB = s * 2 + 1;
    const float inv = 1.0f / (part_l[aA * 128 + hd * 32 + q] +
                              part_l[aB * 128 + hd * 32 + q]);
    const size_t bA = ((size_t)(aA * 4 + hd) * 32 + q) * 64 + dh;
    const size_t bB = ((size_t)(aB * 4 + hd) * 32 + q) * 64 + dh;
    const int hfull = g + 4 * hd;
    const size_t ob = ((size_t)(b * T_SEQ + t * 32 + q)) * 1024 + hfull * 64 + dh;
#pragma unroll
    for (int cc = 0; cc < 4; ++cc) {
        const uint4 ua = *reinterpret_cast<const uint4*>(&part_o[bA + cc * 8]);
        const uint4 ub = *reinterpret_cast<const uint4*>(&part_o[bB + cc * 8]);
        uint4 uo;
        const unsigned* pa = &ua.x;
        const unsigned* pb = &ub.x;
        unsigned* po = &uo.x;
#pragma unroll
        for (int e = 0; e < 4; ++e) {
            const float f0 = (bf2f(pa[e] & 0xffffu) + bf2f(pb[e] & 0xffffu)) * inv;
            const float f1 = (bf2f(pa[e] >> 16) + bf2f(pb[e] >> 16)) * inv;
            po[e] = (unsigned)f2bf(f0) | ((unsigned)f2bf(f1) << 16);
        }
        *reinterpret_cast<uint4*>(&ctx[ob + cc * 8]) = uo;
    }
}

// ---------------------------------------------------------------------------
extern "C" void kernel_launch(void* const* d_in, const int* in_sizes, int n_in,
                              void* d_out, int out_size, void* d_ws, size_t ws_size,
                              hipStream_t stream) {
    const float* x  = (const float*)d_in[0];
    const float* Wq = (const float*)d_in[1];
    const float* Wk = (const float*)d_in[2];
    const float* Wv = (const float*)d_in[3];
    const float* Wp = (const float*)d_in[4];
    const float* bp = (const float*)d_in[5];

    const int M = B_SZ * T_SEQ;  // 4096

    ushort* ws    = (ushort*)d_ws;
    ushort* xb    = ws;                   // 4096x1024
    ushort* Wqkvt = xb + 4194304;         // 896x1024 (rows: Wq^T | Wk^T | Wv^T)
    ushort* Wpt   = Wqkvt + 917504;       // 1024x1024
    ushort* qkv   = Wpt + 1048576;        // 4096x896 (V region unused)
    ushort* vTb   = qkv + 3670016;        // 2x256x2048
    ushort* cbuf  = vTb + 1048576;        // 4096x1024
    ushort* parto = cbuf + 4194304;       // 1024 areas x 4 hd x 32 q x 64 d bf16
    float*  partl = (float*)(parto + 8388608);  // 1024 x 128 f32

    prep_inputs<<<3968, 256, 0, stream>>>(x, xb, Wq, Wk, Wv, Wp, Wqkvt, Wpt);

    gemm_bf16<true, true><<<dim3(7, 64), 256, 0, stream>>>(
        xb, Wqkvt, nullptr, qkv, vTb, M, 896, 1024);

    attn_part<<<1024, 512, 0, stream>>>(qkv, vTb, parto, partl);
    attn_combine<<<512, 256, 0, stream>>>(parto, partl, cbuf);

    gemm_bf16<false, false><<<dim3(8, 64), 256, 0, stream>>>(
        cbuf, Wpt, bp, (float*)d_out, nullptr, M, 1024, 1024);
}

// Round 18
// 83.549 us; speedup vs baseline: 1.1534x; 1.1534x over previous
//
#include <hip/hip_runtime.h>
#include <hip/hip_bf16.h>

#define T_SEQ 2048
#define H_CNT 16
#define B_SZ  2
#define QKV_LD 896
#define KOFF   512
#define VOFF   640

typedef float  f32x4   __attribute__((ext_vector_type(4)));
typedef float  f32x16  __attribute__((ext_vector_type(16)));
typedef __bf16 bf16x8  __attribute__((ext_vector_type(8)));

static __device__ __forceinline__ ushort f2bf(float f) {
    union { float f; unsigned u; } v; v.f = f;
    unsigned u = v.u;
    unsigned r = (u + 0x7fffu + ((u >> 16) & 1u)) >> 16;
    return (ushort)r;
}
static __device__ __forceinline__ unsigned pack2bf(float a, float b) {
    union { __bf16 h[2]; unsigned u; } pk;
    pk.h[0] = (__bf16)a; pk.h[1] = (__bf16)b;
    return pk.u;
}

static __device__ __forceinline__ f32x4 mfma16(bf16x8 a, bf16x8 b, f32x4 c) {
    return __builtin_amdgcn_mfma_f32_16x16x32_bf16(a, b, c, 0, 0, 0);
}
static __device__ __forceinline__ f32x16 mfma32(bf16x8 a, bf16x8 b, f32x16 c) {
    return __builtin_amdgcn_mfma_f32_32x32x16_bf16(a, b, c, 0, 0, 0);
}

// async global->LDS, 16B per lane; LDS dest is wave-uniform base + lane*16
static __device__ __forceinline__ void gl_lds16(const void* g, void* l) {
    __builtin_amdgcn_global_load_lds((const __attribute__((address_space(1))) void*)g,
                                     (__attribute__((address_space(3))) void*)l, 16, 0, 0);
}

// ---------------------------------------------------------------------------
// Fused input prep (one launch): flat grid 3968.
//   n < 2048 : fp32 -> bf16 convert of x (8 elems/thread), block n.
//   n >= 2048: weight transpose fp32 [1024][C] -> bf16 [C][1024];
//              m = n-2048, x-decode = m%60 (Wq<16, Wk<20, Wv<28, Wp), y = m/60.
// ---------------------------------------------------------------------------
__global__ __launch_bounds__(256) void prep_inputs(const float* __restrict__ xin,
                                                   ushort* __restrict__ xb,
                                                   const float* __restrict__ Wq,
                                                   const float* __restrict__ Wk,
                                                   const float* __restrict__ Wv,
                                                   const float* __restrict__ Wp,
                                                   ushort* __restrict__ Wqkvt,
                                                   ushort* __restrict__ Wpt) {
    __shared__ float tile[32][33];
    const int n = blockIdx.x;
    if (n < 2048) {
        const int i = n * 256 + threadIdx.x;
        const float4 v0 = reinterpret_cast<const float4*>(xin)[i * 2];
        const float4 v1 = reinterpret_cast<const float4*>(xin)[i * 2 + 1];
        uint4 o;
        o.x = (unsigned)f2bf(v0.x) | ((unsigned)f2bf(v0.y) << 16);
        o.y = (unsigned)f2bf(v0.z) | ((unsigned)f2bf(v0.w) << 16);
        o.z = (unsigned)f2bf(v1.x) | ((unsigned)f2bf(v1.y) << 16);
        o.w = (unsigned)f2bf(v1.z) | ((unsigned)f2bf(v1.w) << 16);
        reinterpret_cast<uint4*>(xb)[i] = o;
        return;
    }
    const int m = n - 2048;
    const int x = m % 60;
    const int y = m / 60;
    const float* src; ushort* dst; int C, cx;
    if (x < 16)      { src = Wq; dst = Wqkvt;              C = 512;  cx = x; }
    else if (x < 20) { src = Wk; dst = Wqkvt + 512 * 1024; C = 128;  cx = x - 16; }
    else if (x < 28) { src = Wv; dst = Wqkvt + 640 * 1024; C = 256;  cx = x - 20; }
    else             { src = Wp; dst = Wpt;                C = 1024; cx = x - 28; }
    const int tx = threadIdx.x & 31, ty = threadIdx.x >> 5;
    const int r0 = y * 32, c0 = cx * 32;
#pragma unroll
    for (int i = 0; i < 32; i += 8)
        tile[ty + i][tx] = src[(size_t)(r0 + ty + i) * C + c0 + tx];
    __syncthreads();
#pragma unroll
    for (int i = 0; i < 32; i += 8)
        dst[(size_t)(c0 + ty + i) * 1024 + r0 + tx] = f2bf(tile[tx][ty + i]);
}

// ---------------------------------------------------------------------------
// bf16 MFMA GEMM (R13/R16-proven structure): global_load_lds staging,
// BK=128 (32 MFMA per barrier pair). C = A[M,K] @ Bt[N,K]^T.
// Tile 64x128, 4 waves (2x2), wave tile 32x64. LDS 48 KB -> 2-3 blocks/CU.
// V_SPLIT (QKV GEMM only): output cols >= 640 are the V projection; each
// thread's acc[m][n][0..3] = 4 CONSECUTIVE rows at one fixed col, i.e. 4
// consecutive ushorts of vTb[b][col-640][.] -> single aligned 8-B store
// (fused transpose; those cols skip the qkv write).
// ---------------------------------------------------------------------------
template <bool OUT_BF16, bool V_SPLIT>
__global__ __launch_bounds__(256) void gemm_bf16(const ushort* __restrict__ A,
                                                 const ushort* __restrict__ Bt,
                                                 const float* __restrict__ bias,
                                                 void* __restrict__ Cout,
                                                 ushort* __restrict__ vTb,
                                                 int M, int N, int K) {
    __shared__ __align__(16) ushort As[4][64 * 32];
    __shared__ __align__(16) ushort Bs[4][128 * 32];

    const int tid = threadIdx.x;
    const int w = tid >> 6, l = tid & 63;
    const int bm = blockIdx.y * 64, bn = blockIdx.x * 128;
    const int wr = (w >> 1) * 32, wc = (w & 1) * 64;
    const int lr = l & 15, lk = (l >> 4) * 8;
    const int crow = l >> 2, ck8 = (l & 3) * 8;

    const ushort* Ag  = A + (size_t)(bm + w * 16 + crow) * K + ck8;
    const ushort* Bg0 = Bt + (size_t)(bn + w * 16 + crow) * K + ck8;
    const ushort* Bg1 = Bt + (size_t)(bn + (w + 4) * 16 + crow) * K + ck8;

    f32x4 acc[2][4];
#pragma unroll
    for (int m = 0; m < 2; ++m)
#pragma unroll
        for (int n = 0; n < 4; ++n) acc[m][n] = (f32x4){0.f, 0.f, 0.f, 0.f};

    for (int k0 = 0; k0 < K; k0 += 128) {
        __syncthreads();   // prior iteration's LDS reads complete
#pragma unroll
        for (int kk = 0; kk < 4; ++kk) {
            gl_lds16(Ag + k0 + kk * 32, &As[kk][w * 16 * 32]);
            gl_lds16(Bg0 + k0 + kk * 32, &Bs[kk][w * 16 * 32]);
            gl_lds16(Bg1 + k0 + kk * 32, &Bs[kk][(w + 4) * 16 * 32]);
        }
        __syncthreads();   // vmcnt drained before barrier -> tiles ready

#pragma unroll
        for (int kk = 0; kk < 4; ++kk) {
            bf16x8 af[2], bfr[4];
#pragma unroll
            for (int m = 0; m < 2; ++m)
                af[m] = *reinterpret_cast<const bf16x8*>(&As[kk][(wr + m * 16 + lr) * 32 + lk]);
#pragma unroll
            for (int n = 0; n < 4; ++n)
                bfr[n] = *reinterpret_cast<const bf16x8*>(&Bs[kk][(wc + n * 16 + lr) * 32 + lk]);
#pragma unroll
            for (int m = 0; m < 2; ++m)
#pragma unroll
                for (int n = 0; n < 4; ++n)
                    acc[m][n] = mfma16(af[m], bfr[n], acc[m][n]);
        }
    }

    const int orow = bm + wr + (l >> 4) * 4;
    const int ocol0 = bn + wc + lr;
#pragma unroll
    for (int m = 0; m < 2; ++m)
#pragma unroll
        for (int n = 0; n < 4; ++n) {
            const int col = ocol0 + n * 16;
            if (V_SPLIT && col >= VOFF) {
                // fused V transpose: 4 consecutive rows at fixed col
                uint2 pk;
                pk.x = (unsigned)f2bf(acc[m][n][0]) | ((unsigned)f2bf(acc[m][n][1]) << 16);
                pk.y = (unsigned)f2bf(acc[m][n][2]) | ((unsigned)f2bf(acc[m][n][3]) << 16);
                const int row0 = orow + m * 16;
                const size_t vidx = (size_t)(row0 >> 11) * 524288 +
                                    (size_t)(col - VOFF) * 2048 + (row0 & 2047);
                *reinterpret_cast<uint2*>(&vTb[vidx]) = pk;
                continue;
            }
            const float bv = OUT_BF16 ? 0.0f : bias[col];
#pragma unroll
            for (int r = 0; r < 4; ++r) {
                const size_t idx = (size_t)(orow + m * 16 + r) * N + col;
                if constexpr (OUT_BF16)
                    reinterpret_cast<ushort*>(Cout)[idx] = f2bf(acc[m][n][r]);
                else
                    reinterpret_cast<float*>(Cout)[idx] = acc[m][n][r] + bv;
            }
        }
}

// ---------------------------------------------------------------------------
// Flash attention (R13/R16-verified attn_mfma9, byte-identical): 128-key
// staged tiles at 512 threads. Block = (tp, g, b), 8 waves: head hd=w&3
// (h=g+4*hd), key-half grp=w>>2; wave computes subtiles si={grp,2+grp}.
// Phases: q-tile 63-tp then tp (~17 stage iters/block, uniform).
// 1-barrier double-buffer staging; 2-way cross-grp combine via LDS.
// ---------------------------------------------------------------------------
#define LDK 40
#define LDV 136

__global__ __launch_bounds__(512) void attn_mfma9(const ushort* __restrict__ qkv,
                                                  const ushort* __restrict__ vT,
                                                  ushort* __restrict__ ctx) {
    __shared__ __align__(16) ushort Ks[2][128 * LDK];   // 20.5 KB
    __shared__ __align__(16) ushort Vs[2][64 * LDV];    // 34.8 KB
    __shared__ float lsred[4][32];

    const int tid = threadIdx.x;
    const int w = tid >> 6, l = tid & 63;
    const int lq = l & 31;
    const int hi = l >> 5;
    const int tp = blockIdx.x, g = blockIdx.y, b = blockIdx.z;
    const int hd = w & 3, grp = w >> 2;
    const int h = g + 4 * hd;

    const float slope = exp2f(-0.5f * (float)(h + 1));
    const float k1 = 0.17677669529663687f * 1.4426950408889634f;  // scale*log2e
    const float k2 = slope * k1;
    const int Wint = (int)(275.0f / slope);

    // K staging: row ksd of 128, chunk kc4 of 4
    const int ksd = tid >> 2, kc4 = tid & 3;
    const ushort* kgp = qkv + (size_t)b * T_SEQ * QKV_LD + KOFF + g * 32 +
                        (size_t)ksd * QKV_LD + kc4 * 8;
    // V staging: d-row vsd of 64, vj of 8 -> spans {vs0, vs0+1}, chunk vc4
    const int vsd = tid >> 3, vj = tid & 7;
    const int vs0 = (vj >> 2) << 1, vc4 = vj & 3;
    const int voff = (vc4 & 1) * 4 + (vc4 >> 1) * 16;  // permuted slot (ushorts)
    const ushort* vgp = vT + ((size_t)b * 256 + g * 64 + vsd) * T_SEQ + vs0 * 32 + vc4 * 8;
    const int vl0 = vsd * LDV + vs0 * 32 + voff;
    const int vl1 = vsd * LDV + (vs0 + 1) * 32 + voff;

    // combine scratch (16 KB), aliased onto Vs after loop reads complete
    float* red = reinterpret_cast<float*>(&Vs[0][0]);
    const int sidx = (hd * 64 + l) * 16;

    int cur = 0;
    for (int ph = 0; ph < 2; ++ph) {
        const int t = ph ? tp : (63 - tp);
        const int i0 = t * 32;
        const int nkeys = i0 + 32;
        const int jtmax = (nkeys + 127) & ~127;

        const ushort* qrow = qkv + ((size_t)(b * T_SEQ + i0 + lq)) * QKV_LD + h * 32 + hi * 8;
        const bf16x8 qa = *reinterpret_cast<const bf16x8*>(qrow);
        const bf16x8 qb = *reinterpret_cast<const bf16x8*>(qrow + 16);

        f32x16 o0, o1;
#pragma unroll
        for (int r = 0; r < 16; ++r) { o0[r] = 0.0f; o1[r] = 0.0f; }
        float ls = 0.0f;

        // phase prologue loads (guarded at 32-key granularity)
        uint4 kreg, vr0, vr1;
        if (ksd < nkeys) kreg = *reinterpret_cast<const uint4*>(kgp);
        vr0 = *reinterpret_cast<const uint4*>(vgp);          // vs0*32 < 32 <= nkeys always
        if (vs0 * 32 + 32 < nkeys) vr1 = *reinterpret_cast<const uint4*>(vgp + 32);

        for (int jt = 0; jt < jtmax; jt += 128) {
            // ---- stage buf[cur] ----
            *reinterpret_cast<uint4*>(&Ks[cur][ksd * LDK + kc4 * 8]) = kreg;
            *reinterpret_cast<uint2*>(&Vs[cur][vl0]) = make_uint2(vr0.x, vr0.y);
            *reinterpret_cast<uint2*>(&Vs[cur][vl0 + 8]) = make_uint2(vr0.z, vr0.w);
            *reinterpret_cast<uint2*>(&Vs[cur][vl1]) = make_uint2(vr1.x, vr1.y);
            *reinterpret_cast<uint2*>(&Vs[cur][vl1 + 8]) = make_uint2(vr1.z, vr1.w);
            // ---- issue next-tile loads (guarded) ----
            const int jn = jt + 128;
            if (jn < jtmax) {
                if (jn + ksd < nkeys)
                    kreg = *reinterpret_cast<const uint4*>(kgp + (size_t)jn * QKV_LD);
                if (jn + vs0 * 32 < nkeys)
                    vr0 = *reinterpret_cast<const uint4*>(vgp + jn);
                if (jn + vs0 * 32 + 32 < nkeys)
                    vr1 = *reinterpret_cast<const uint4*>(vgp + jn + 32);
            }
            __syncthreads();   // buf[cur] ready

#pragma unroll
            for (int s = 0; s < 2; ++s) {
                const int si = s * 2 + grp;
                const int jts = jt + si * 32;
                if (jts < nkeys && jts + 31 >= i0 - Wint) {
                    const bf16x8 ka = *reinterpret_cast<const bf16x8*>(&Ks[cur][(si * 32 + lq) * LDK + hi * 8]);
                    const bf16x8 kb2 = *reinterpret_cast<const bf16x8*>(&Ks[cur][(si * 32 + lq) * LDK + 16 + hi * 8]);
                    f32x16 p;
#pragma unroll
                    for (int r = 0; r < 16; ++r) p[r] = 0.0f;
                    __builtin_amdgcn_s_setprio(1);
                    p = mfma32(ka, qa, p);
                    p = mfma32(kb2, qb, p);
                    __builtin_amdgcn_s_setprio(0);

                    const int dlt = jts + 4 * hi - i0 - lq;
                    const float base2 = k2 * (float)dlt;
                    float pe[16];
                    if (jts + 31 > i0) {   // diag subtile (uniform branch)
#pragma unroll
                        for (int r = 0; r < 16; ++r) {
                            const int off = (r & 3) + 8 * (r >> 2);
                            const float arg = fmaf(p[r], k1, fmaf((float)off, k2, base2));
                            float e = exp2f(arg);
                            if (dlt + off > 0) e = 0.0f;
                            ls += e;
                            pe[r] = e;
                        }
                    } else {
#pragma unroll
                        for (int r = 0; r < 16; ++r) {
                            const int off = (r & 3) + 8 * (r >> 2);
                            const float arg = fmaf(p[r], k1, fmaf((float)off, k2, base2));
                            const float e = exp2f(arg);
                            ls += e;
                            pe[r] = e;
                        }
                    }
                    union { unsigned u[4]; bf16x8 v; } A1, A2;
#pragma unroll
                    for (int j2 = 0; j2 < 4; ++j2) A1.u[j2] = pack2bf(pe[2 * j2], pe[2 * j2 + 1]);
#pragma unroll
                    for (int j2 = 0; j2 < 4; ++j2) A2.u[j2] = pack2bf(pe[8 + 2 * j2], pe[9 + 2 * j2]);

                    const int vr0i = lq * LDV + si * 32;
                    const int vr1i = (32 + lq) * LDV + si * 32;
                    const bf16x8 v00 = *reinterpret_cast<const bf16x8*>(&Vs[cur][vr0i + hi * 8]);
                    const bf16x8 v01 = *reinterpret_cast<const bf16x8*>(&Vs[cur][vr0i + 16 + hi * 8]);
                    const bf16x8 v10 = *reinterpret_cast<const bf16x8*>(&Vs[cur][vr1i + hi * 8]);
                    const bf16x8 v11 = *reinterpret_cast<const bf16x8*>(&Vs[cur][vr1i + 16 + hi * 8]);
                    __builtin_amdgcn_s_setprio(1);
                    o0 = mfma32(A1.v, v00, o0);
                    o0 = mfma32(A2.v, v01, o0);
                    o1 = mfma32(A1.v, v10, o1);
                    o1 = mfma32(A2.v, v11, o1);
                    __builtin_amdgcn_s_setprio(0);
                }
            }
            cur ^= 1;
        }

        // ---- 2-way cross-grp combine (proven tree) ----
        const float ls2 = ls + __shfl_xor(ls, 32);
        __syncthreads();   // all loop reads of Vs done -> safe to reuse
        if (grp == 0) {
#pragma unroll
            for (int r = 0; r < 16; ++r) red[sidx + r] = o0[r];
            if (hi == 0) lsred[hd][lq] = ls2;
        }
        __syncthreads();
        float inv = 0.0f;
        if (grp == 1) {
#pragma unroll
            for (int r = 0; r < 16; ++r) o0[r] += red[sidx + r];
            inv = 1.0f / (ls2 + lsred[hd][lq]);
        }
        __syncthreads();
        if (grp == 0) {
#pragma unroll
            for (int r = 0; r < 16; ++r) red[sidx + r] = o1[r];
        }
        __syncthreads();
        if (grp == 1) {
#pragma unroll
            for (int r = 0; r < 16; ++r) o1[r] += red[sidx + r];
#pragma unroll
            for (int r = 0; r < 16; ++r) {
                const int qr = (r & 3) + 8 * (r >> 2) + 4 * hi;
                const float invq = __shfl(inv, qr);
                const size_t row = (size_t)(b * T_SEQ + i0 + qr);
                ctx[row * 1024 + h * 64 + lq] = f2bf(o0[r] * invq);
                ctx[row * 1024 + h * 64 + 32 + lq] = f2bf(o1[r] * invq);
            }
        }
        __syncthreads();   // scratch reads done before next phase stages
    }
}

// ---------------------------------------------------------------------------
extern "C" void kernel_launch(void* const* d_in, const int* in_sizes, int n_in,
                              void* d_out, int out_size, void* d_ws, size_t ws_size,
                              hipStream_t stream) {
    const float* x  = (const float*)d_in[0];
    const float* Wq = (const float*)d_in[1];
    const float* Wk = (const float*)d_in[2];
    const float* Wv = (const float*)d_in[3];
    const float* Wp = (const float*)d_in[4];
    const float* bp = (const float*)d_in[5];

    const int M = B_SZ * T_SEQ;  // 4096

    ushort* ws    = (ushort*)d_ws;
    ushort* xb    = ws;                   // 4096x1024
    ushort* Wqkvt = xb + 4194304;         // 896x1024 (rows: Wq^T | Wk^T | Wv^T)
    ushort* Wpt   = Wqkvt + 917504;       // 1024x1024
    ushort* qkv   = Wpt + 1048576;        // 4096x896 (V region unused now)
    ushort* vTb   = qkv + 3670016;        // 2x256x2048
    ushort* cbuf  = vTb + 1048576;        // 4096x1024

    prep_inputs<<<3968, 256, 0, stream>>>(x, xb, Wq, Wk, Wv, Wp, Wqkvt, Wpt);

    gemm_bf16<true, true><<<dim3(7, 64), 256, 0, stream>>>(
        xb, Wqkvt, nullptr, qkv, vTb, M, 896, 1024);

    attn_mfma9<<<dim3(32, 4, B_SZ), 512, 0, stream>>>(qkv, vTb, cbuf);

    gemm_bf16<false, false><<<dim3(8, 64), 256, 0, stream>>>(
        cbuf, Wpt, bp, (float*)d_out, nullptr, M, 1024, 1024);
}